// Round 14
// baseline (100.756 us; speedup 1.0000x reference)
//
#include <hip/hip_runtime.h>
#include <hip/hip_bf16.h>
#include <math.h>

// Problem constants (fixed by setup_inputs)
#define B_  2
#define NH  4
#define HH  64
#define WW  64
#define KD  32
#define L_  4096            // HH*WW
#define BN_ 8               // B_*NH
#define LOG2E 1.4426950408889634f
#define KSCALE (0.17677669529663687f * 1.4426950408889634f)  // log2e/sqrt(32)
#define FIXED_M 10.0f   // log2-domain fixed softmax shift (shift-invariant =>
                        // exact); scores max ~3, p=2^(s-10) f16-safe to s>26.

typedef float    f32x4  __attribute__((ext_vector_type(4), may_alias));
typedef _Float16 half8  __attribute__((ext_vector_type(8), may_alias));
typedef _Float16 half4  __attribute__((ext_vector_type(4), may_alias));
typedef __fp16   fp16x2 __attribute__((ext_vector_type(2)));
typedef unsigned uint4v __attribute__((ext_vector_type(4), may_alias));

__device__ __forceinline__ float fexp2(float x) {
#if __has_builtin(__builtin_amdgcn_exp2f)
    return __builtin_amdgcn_exp2f(x);
#else
    return __expf(x * 0.69314718056f);
#endif
}

__device__ __forceinline__ unsigned pack2u(float a, float b) {
    fp16x2 t = __builtin_amdgcn_cvt_pkrtz(a, b);   // v_cvt_pkrtz_f16_f32
    union { fp16x2 i; unsigned o; } u;
    u.i = t;
    return u.o;
}

// ---------------------------------------------------------------------------
// Kernel A: qkv = x @ w_qkv (M=8192,K=128,N=384), f16 MFMA, single LDS pass
// (K=128), wsT-staged. Outputs: q_h/k_h [bn][l][32] (k pre-scaled),
// TILE-PACKED V (R13 layout).
// ---------------------------------------------------------------------------
__global__ __launch_bounds__(256) void qkv_gemm(const float* __restrict__ x,
                                                const float* __restrict__ w,
                                                _Float16* __restrict__ q_h,
                                                _Float16* __restrict__ k_h,
                                                _Float16* __restrict__ vt_h) {
    __shared__ __align__(16) char smem[34816];
    _Float16* xs  = (_Float16*)smem;            // [64][136]
    _Float16* wsT = (_Float16*)(smem + 17408);  // [64][136] transposed w

    const int mt = blockIdx.x % 128;
    const int nt = blockIdx.x / 128;
    const int m0 = mt * 64, n0 = nt * 64;
    const int tid = threadIdx.x;
    const int wv = tid >> 6, lane = tid & 63;
    const int l16 = lane & 15, quad = lane >> 4;

    #pragma unroll
    for (int i = 0; i < 8; i++) {
        const int idx = i * 256 + tid;
        const int row = idx >> 5, c4 = (idx & 31) * 4;
        const float4 v = *(const float4*)&x[(size_t)(m0 + row) * 128 + c4];
        half4 h;
        h[0] = (_Float16)v.x; h[1] = (_Float16)v.y;
        h[2] = (_Float16)v.z; h[3] = (_Float16)v.w;
        *(half4*)&xs[row * 136 + c4] = h;
    }
    #pragma unroll
    for (int i = 0; i < 8; i++) {
        const int idx = i * 256 + tid;
        const int k = idx >> 4, c4 = (idx & 15) * 4;
        const float4 v = *(const float4*)&w[(size_t)k * 384 + n0 + c4];
        wsT[(c4 + 0) * 136 + k] = (_Float16)v.x;
        wsT[(c4 + 1) * 136 + k] = (_Float16)v.y;
        wsT[(c4 + 2) * 136 + k] = (_Float16)v.z;
        wsT[(c4 + 3) * 136 + k] = (_Float16)v.w;
    }
    __syncthreads();

    f32x4 acc[4] = {{0.f,0.f,0.f,0.f},{0.f,0.f,0.f,0.f},
                    {0.f,0.f,0.f,0.f},{0.f,0.f,0.f,0.f}};
    half8 af[4];
    #pragma unroll
    for (int kc = 0; kc < 4; kc++)
        af[kc] = *(const half8*)&xs[(wv * 16 + l16) * 136 + kc * 32 + quad * 8];
    #pragma unroll
    for (int ns = 0; ns < 4; ns++)
        #pragma unroll
        for (int kc = 0; kc < 4; kc++) {
            const half8 bf = *(const half8*)&wsT[(ns * 16 + l16) * 136 + kc * 32 + quad * 8];
            acc[ns] = __builtin_amdgcn_mfma_f32_16x16x32_f16(af[kc], bf, acc[ns], 0, 0, 0);
        }

    const int which = n0 >> 7;                 // 0=q, 1=k, 2=v
    const int nc = n0 & 127;
    const int b = m0 >> 12;
    if (which < 2) {
        _Float16* dst = (which == 0) ? q_h : k_h;
        const float mult = (which == 1) ? KSCALE : 1.0f;
        #pragma unroll
        for (int ns = 0; ns < 4; ns++) {
            const int col = nc + ns * 16 + l16;
            const int bn = b * NH + (col >> 5);
            const int d = col & 31;
            #pragma unroll
            for (int r = 0; r < 4; r++) {
                const int l = (m0 & 4095) + wv * 16 + quad * 4 + r;
                dst[((size_t)bn * L_ + l) * 32 + d] = (_Float16)(acc[ns][r] * mult);
            }
        }
    } else {
        __syncthreads();                        // xs dead -> overlay img
        float* img = (float*)smem;
        #pragma unroll
        for (int ns = 0; ns < 4; ns++) {
            const int chan = ns * 16 + l16;
            const int h = chan >> 5, d = chan & 31;
            #pragma unroll
            for (int r = 0; r < 4; r++) {
                const int p = wv * 16 + quad * 4 + r;
                const int y = p >> 5, p32 = p & 31;
                const int q4 = (p32 >> 2) & 3;
                const int j = ((p32 >> 4) & 1) * 4 + (p32 & 3);
                const int fidx = h * 2048 + (y * 2 + (d >> 4)) * 512
                               + (q4 * 16 + (d & 15)) * 8 + j;
                img[fidx + (fidx >> 4)] = acc[ns][r];
            }
        }
        __syncthreads();
        const int ktg = (m0 & 4095) >> 6;
        #pragma unroll
        for (int h = 0; h < 2; h++) {
            const int head = (nc >> 5) + h;
            const int bn = b * NH + head;
            const int fbase = h * 2048 + tid * 8;
            const int sbase = fbase + (fbase >> 4);
            half8 o;
            #pragma unroll
            for (int e = 0; e < 8; e++) o[e] = (_Float16)img[sbase + e];
            *(half8*)(vt_h + (size_t)bn * 131072 + ktg * 2048 + tid * 8) = o;
        }
    }
}

// ---------------------------------------------------------------------------
// Kernel B: LDS-staged flash attention. R34: TWO INDEPENDENT BARRIER DOMAINS
// per CU with the R30 body. Evidence chain: read-volume (R30), wave count
// (R27/R28), barrier count (R33) all NULL -> the stall is the post-barrier
// convoy (all 4 waves/SIMD aligned: LDS burst, then trans/exp burst, then
// MFMA, each serialized across waves). The only measured de-convoy lever is
// independent block domains (R27: +6%), blocked since LDS >80KB. R34: 8-wave
// blocks (4 kq x 2 qgp), ONE w1 each, grid 512 = 2 blocks/CU at 16 waves/CU;
// two blocks drift freely so one block's exp phase overlaps the other's
// MFMA/LDS phase. LDS = 2buf x 32KB stage + 4 R-tables [16][64] f32 XOR
// (R33-verified, col=kt^row) = 81920B -> 2 blocks fit (163840 = cap).
// Each wave stages ONE full 4KB tile (4x 1KB chunks, lane-stride 16B).
// launch_bounds(512,4) pins the proven 128-reg budget.
// ---------------------------------------------------------------------------
__global__ __launch_bounds__(512, 4) void attn_mfma(
    const _Float16* __restrict__ q_h,    // [bn][l][32]
    const _Float16* __restrict__ k_h,    // [bn][l][32] pre-scaled
    const _Float16* __restrict__ vt_h,   // [bn][kt][2048] tile-packed
    const float* __restrict__ emb_h,     // [127][32] f32
    const float* __restrict__ emb_w,     // [127][32] f32
    float* __restrict__ out)
{
    // [0,65536): K/V stage, 2 bufs x 32KB; per buffer:
    //   [0,16K) K quarters 0..3 (4KB each) | [16K,32K) V quarters 0..3
    // [65536,81920): 4 R-tables [16][64] f32, col XOR-swizzled by row
    __shared__ __align__(16) char smem[81920];

    const int bi    = blockIdx.x;
    const int bn    = bi & 7;            // XCD swizzle: one bn per XCD
    const int w1    = bi >> 3;           // 0..63
    const int tid   = threadIdx.x;
    const int wv    = tid >> 6;          // 0..7
    const int kq    = wv >> 1;           // key quarter 0..3 (16-tile ring)
    const int qgp   = wv & 1;            // q-group pair
    const int lane  = tid & 63;
    const int l16   = lane & 15;
    const int quad  = lane >> 4;
    const int q0A   = (qgp * 2 + 0) * 16;   // h1 base, q-group A
    const int q0B   = (qgp * 2 + 1) * 16;   // h1 base, q-group B

    const _Float16* Kbase = k_h  + (size_t)bn * L_ * 32;
    const _Float16* Vtile = vt_h + (size_t)bn * 131072;

    // ---- staging: category = wv = (kqS, isVS); wave stages one full 4KB
    //      tile per step as 4x 1KB chunks (lane-stride 16B pattern) ----
    const int kqS  = wv & 3;
    const int isVS = wv >> 2;
    const _Float16* gsrc = (isVS ? Vtile : Kbase) + (size_t)kqS * 16 * 2048;
    const _Float16* gs[4];
    int ldsT[4];
    #pragma unroll
    for (int u = 0; u < 4; u++) {
        gs[u] = gsrc + u * 512 + lane * 8;
        ldsT[u] = kqS * 4096 + isVS * 16384 + (isVS
            ? (u * 1024 + lane * 16)
            : ((u * 16 + (lane >> 2)) * 64 + (((lane & 3) ^ ((lane >> 3) & 3)) << 4)));
    }

    // ---- prologue: issue stage for tile 0 (hides under R-phase) ----
    uint4v stg0[4];
    #pragma unroll
    for (int u = 0; u < 4; u++) stg0[u] = *(const uint4v*)gs[u];

    // R tables [16][64] f32, col-swizzled (store col = kt ^ row)
    float* RwA = (float*)(smem + 65536) + (qgp * 2 + 0) * 1024;
    float* RwB = (float*)(smem + 65536) + (qgp * 2 + 1) * 1024;

    const half8 aq0 = *(const half8*)(q_h +
        (((size_t)bn * L_ + (q0A + l16) * 64 + w1) * 32 + quad * 8));
    const half8 aq1 = *(const half8*)(q_h +
        (((size_t)bn * L_ + (q0B + l16) * 64 + w1) * 32 + quad * 8));

    f32x4 qwT0[4], qwT1[4];
    #pragma unroll
    for (int sub = 0; sub < 4; sub++) {
        const float* ew = emb_w + (size_t)(sub * 16 + l16 - w1 + 63) * 32 + quad * 8;
        const float4 e0 = *(const float4*)ew;
        const float4 e1 = *(const float4*)(ew + 4);
        union { uint4v u; half8 h; } ua;
        ua.u[0] = pack2u(e0.x * LOG2E, e0.y * LOG2E);
        ua.u[1] = pack2u(e0.z * LOG2E, e0.w * LOG2E);
        ua.u[2] = pack2u(e1.x * LOG2E, e1.y * LOG2E);
        ua.u[3] = pack2u(e1.z * LOG2E, e1.w * LOG2E);
        f32x4 z = {-FIXED_M, -FIXED_M, -FIXED_M, -FIXED_M};
        qwT0[sub] = __builtin_amdgcn_mfma_f32_16x16x32_f16(ua.h, aq0, z, 0, 0, 0);
        qwT1[sub] = __builtin_amdgcn_mfma_f32_16x16x32_f16(ua.h, aq1, z, 0, 0, 0);
    }

    // h-bias fill: kt-indexed, predicated, XOR-swizzled col. Wave (kq,qgp)
    // covers jt = kq*2+ji for BOTH its q-group tables; 4 kq waves -> j 0..127.
    #pragma unroll
    for (int ji = 0; ji < 2; ji++) {
        const int jt = kq * 2 + ji;
        const int j = min(jt * 16 + l16, 126);
        const float* eh = emb_h + (size_t)j * 32 + quad * 8;
        const float4 e0 = *(const float4*)eh;
        const float4 e1 = *(const float4*)(eh + 4);
        union { uint4v u; half8 h; } ub;
        ub.u[0] = pack2u(e0.x * LOG2E, e0.y * LOG2E);
        ub.u[1] = pack2u(e0.z * LOG2E, e0.w * LOG2E);
        ub.u[2] = pack2u(e1.x * LOG2E, e1.y * LOG2E);
        ub.u[3] = pack2u(e1.z * LOG2E, e1.w * LOG2E);
        f32x4 z = {0.f, 0.f, 0.f, 0.f};
        const f32x4 C0 = __builtin_amdgcn_mfma_f32_16x16x32_f16(aq0, ub.h, z, 0, 0, 0);
        const f32x4 C1 = __builtin_amdgcn_mfma_f32_16x16x32_f16(aq1, ub.h, z, 0, 0, 0);
        #pragma unroll
        for (int r = 0; r < 4; r++) {
            const int row = quad * 4 + r;
            const int cA = jt * 16 + l16 - 63 + (q0A + row);   // = kt
            if (cA >= 0 && cA < 64) RwA[row * 64 + (cA ^ row)] = C0[r];
            const int cB = jt * 16 + l16 - 63 + (q0B + row);
            if (cB >= 0 && cB < 64) RwB[row * 64 + (cB ^ row)] = C1[r];
        }
    }

    // write prologue stage (vmcnt wait is ~free: issued way up top)
    #pragma unroll
    for (int u = 0; u < 4; u++) *(uint4v*)(smem + ldsT[u]) = stg0[u];
    __syncthreads();    // R tables + step-0 tiles ready

    f32x4 O00 = {0.f,0.f,0.f,0.f}, O01 = {0.f,0.f,0.f,0.f};   // g=0
    f32x4 O10 = {0.f,0.f,0.f,0.f}, O11 = {0.f,0.f,0.f,0.f};   // g=1
    float la = 0.f, lb = 0.f;
#if __has_builtin(__builtin_amdgcn_fdot2)
    fp16x2 onep;
    { union { unsigned u; fp16x2 h; } uo; uo.u = pack2u(1.0f, 1.0f); onep = uo.h; }
#endif

    // per-lane read offsets (constant across steps)
    const int swz16 = ((quad ^ ((l16 >> 1) & 3)) << 4);
    const int kOff = kq * 4096 + l16 * 64 + swz16;
    const int vOff = 16384 + kq * 4096 + lane * 16;

    #pragma unroll 2
    for (int t = 0; t < 16; t++) {
        const int cur = t & 1;
        const int tS = (t < 15) ? (t + 1) : 15;       // clamp: last re-reads t15
        // ---- issue next-step stage loads (latency hides under compute) ----
        uint4v sa[4];
        #pragma unroll
        for (int u = 0; u < 4; u++)
            sa[u] = *(const uint4v*)(gs[u] + (size_t)tS * 2048);

        const char* kb = smem + cur * 32768 + kOff;
        const char* vb = smem + cur * 32768 + vOff;
        const half8 kf0 = *(const half8*)(kb);
        const half8 kf1 = *(const half8*)(kb + 1024);
        const half8 kf2 = *(const half8*)(kb + 2048);
        const half8 kf3 = *(const half8*)(kb + 3072);
        const half8 va00 = *(const half8*)(vb);
        const half8 va10 = *(const half8*)(vb + 1024);
        const half8 va01 = *(const half8*)(vb + 2048);
        const half8 va11 = *(const half8*)(vb + 3072);

        // ---- S for both q-groups from the SAME kf reads ----
        const f32x4 S00 = __builtin_amdgcn_mfma_f32_16x16x32_f16(kf0, aq0, qwT0[0], 0, 0, 0);
        const f32x4 S01 = __builtin_amdgcn_mfma_f32_16x16x32_f16(kf1, aq0, qwT0[1], 0, 0, 0);
        const f32x4 S02 = __builtin_amdgcn_mfma_f32_16x16x32_f16(kf2, aq0, qwT0[2], 0, 0, 0);
        const f32x4 S03 = __builtin_amdgcn_mfma_f32_16x16x32_f16(kf3, aq0, qwT0[3], 0, 0, 0);
        const f32x4 S10 = __builtin_amdgcn_mfma_f32_16x16x32_f16(kf0, aq1, qwT1[0], 0, 0, 0);
        const f32x4 S11 = __builtin_amdgcn_mfma_f32_16x16x32_f16(kf1, aq1, qwT1[1], 0, 0, 0);
        const f32x4 S12 = __builtin_amdgcn_mfma_f32_16x16x32_f16(kf2, aq1, qwT1[2], 0, 0, 0);
        const f32x4 S13 = __builtin_amdgcn_mfma_f32_16x16x32_f16(kf3, aq1, qwT1[3], 0, 0, 0);

        const int kt = kq * 16 + t;
        const float qhA = RwA[l16 * 64 + (kt ^ l16)];
        const float qhB = RwB[l16 * 64 + (kt ^ l16)];

        // ---- fixed-m softmax g=0 ----
        union { uint4v u; half8 h; } p0a, p0b;
        {
            const float a0 = fexp2(S00[0] + qhA), a1 = fexp2(S00[1] + qhA);
            const float a2 = fexp2(S00[2] + qhA), a3 = fexp2(S00[3] + qhA);
            const float a4 = fexp2(S01[0] + qhA), a5 = fexp2(S01[1] + qhA);
            const float a6 = fexp2(S01[2] + qhA), a7 = fexp2(S01[3] + qhA);
            p0a.u[0] = pack2u(a0, a1); p0a.u[1] = pack2u(a2, a3);
            p0a.u[2] = pack2u(a4, a5); p0a.u[3] = pack2u(a6, a7);
            const float b0 = fexp2(S02[0] + qhA), b1 = fexp2(S02[1] + qhA);
            const float b2 = fexp2(S02[2] + qhA), b3 = fexp2(S02[3] + qhA);
            const float b4 = fexp2(S03[0] + qhA), b5 = fexp2(S03[1] + qhA);
            const float b6 = fexp2(S03[2] + qhA), b7 = fexp2(S03[3] + qhA);
            p0b.u[0] = pack2u(b0, b1); p0b.u[1] = pack2u(b2, b3);
            p0b.u[2] = pack2u(b4, b5); p0b.u[3] = pack2u(b6, b7);
        }
        // ---- fixed-m softmax g=1 (independent chain) ----
        union { uint4v u; half8 h; } p1a, p1b;
        {
            const float a0 = fexp2(S10[0] + qhB), a1 = fexp2(S10[1] + qhB);
            const float a2 = fexp2(S10[2] + qhB), a3 = fexp2(S10[3] + qhB);
            const float a4 = fexp2(S11[0] + qhB), a5 = fexp2(S11[1] + qhB);
            const float a6 = fexp2(S11[2] + qhB), a7 = fexp2(S11[3] + qhB);
            p1a.u[0] = pack2u(a0, a1); p1a.u[1] = pack2u(a2, a3);
            p1a.u[2] = pack2u(a4, a5); p1a.u[3] = pack2u(a6, a7);
            const float b0 = fexp2(S12[0] + qhB), b1 = fexp2(S12[1] + qhB);
            const float b2 = fexp2(S12[2] + qhB), b3 = fexp2(S12[3] + qhB);
            const float b4 = fexp2(S13[0] + qhB), b5 = fexp2(S13[1] + qhB);
            const float b6 = fexp2(S13[2] + qhB), b7 = fexp2(S13[3] + qhB);
            p1b.u[0] = pack2u(b0, b1); p1b.u[1] = pack2u(b2, b3);
            p1b.u[2] = pack2u(b4, b5); p1b.u[3] = pack2u(b6, b7);
        }

        // ---- PV (MFMA pipe busy while VALU accumulates l below) ----
        O00 = __builtin_amdgcn_mfma_f32_16x16x32_f16(va00, p0a.h, O00, 0, 0, 0);
        O00 = __builtin_amdgcn_mfma_f32_16x16x32_f16(va01, p0b.h, O00, 0, 0, 0);
        O01 = __builtin_amdgcn_mfma_f32_16x16x32_f16(va10, p0a.h, O01, 0, 0, 0);
        O01 = __builtin_amdgcn_mfma_f32_16x16x32_f16(va11, p0b.h, O01, 0, 0, 0);
        O10 = __builtin_amdgcn_mfma_f32_16x16x32_f16(va00, p1a.h, O10, 0, 0, 0);
        O10 = __builtin_amdgcn_mfma_f32_16x16x32_f16(va01, p1b.h, O10, 0, 0, 0);
        O11 = __builtin_amdgcn_mfma_f32_16x16x32_f16(va10, p1a.h, O11, 0, 0, 0);
        O11 = __builtin_amdgcn_mfma_f32_16x16x32_f16(va11, p1b.h, O11, 0, 0, 0);

        // ---- l accumulation (co-issues with PV on the VALU pipe) ----
#if __has_builtin(__builtin_amdgcn_fdot2)
        {
            union { unsigned u; fp16x2 h; } c0, c1, c2, c3;
            c0.u = p0a.u[0]; c1.u = p0a.u[1]; c2.u = p0a.u[2]; c3.u = p0a.u[3];
            la = __builtin_amdgcn_fdot2(c0.h, onep, la, false);
            la = __builtin_amdgcn_fdot2(c1.h, onep, la, false);
            la = __builtin_amdgcn_fdot2(c2.h, onep, la, false);
            la = __builtin_amdgcn_fdot2(c3.h, onep, la, false);
            c0.u = p0b.u[0]; c1.u = p0b.u[1]; c2.u = p0b.u[2]; c3.u = p0b.u[3];
            la = __builtin_amdgcn_fdot2(c0.h, onep, la, false);
            la = __builtin_amdgcn_fdot2(c1.h, onep, la, false);
            la = __builtin_amdgcn_fdot2(c2.h, onep, la, false);
            la = __builtin_amdgcn_fdot2(c3.h, onep, la, false);
            c0.u = p1a.u[0]; c1.u = p1a.u[1]; c2.u = p1a.u[2]; c3.u = p1a.u[3];
            lb = __builtin_amdgcn_fdot2(c0.h, onep, lb, false);
            lb = __builtin_amdgcn_fdot2(c1.h, onep, lb, false);
            lb = __builtin_amdgcn_fdot2(c2.h, onep, lb, false);
            lb = __builtin_amdgcn_fdot2(c3.h, onep, lb, false);
            c0.u = p1b.u[0]; c1.u = p1b.u[1]; c2.u = p1b.u[2]; c3.u = p1b.u[3];
            lb = __builtin_amdgcn_fdot2(c0.h, onep, lb, false);
            lb = __builtin_amdgcn_fdot2(c1.h, onep, lb, false);
            lb = __builtin_amdgcn_fdot2(c2.h, onep, lb, false);
            lb = __builtin_amdgcn_fdot2(c3.h, onep, lb, false);
        }
#endif

        // ---- write staged tile into the other buffer, then step barrier ----
        __builtin_amdgcn_sched_barrier(0);   // keep compute above the write
        #pragma unroll
        for (int u = 0; u < 4; u++)
            *(uint4v*)(smem + (cur ^ 1) * 32768 + ldsT[u]) = sa[u];
        __syncthreads();
    }

    la += __shfl_xor(la, 16);
    la += __shfl_xor(la, 32);
    lb += __shfl_xor(lb, 16);
    lb += __shfl_xor(lb, 32);

    __syncthreads();                     // stage+R dead -> overlay merge
    float (*mO)[32][17] = (float(*)[32][17])smem;     // [slot][d][q16], 16 slots
    float* mL = (float*)(smem + 34816);               // [slot][16]
    const int slot0 = wv * 2 + 0;        // g=0
    const int slot1 = wv * 2 + 1;        // g=1
    #pragma unroll
    for (int r = 0; r < 4; r++) {
        mO[slot0][quad * 4 + r][l16]      = O00[r];
        mO[slot0][16 + quad * 4 + r][l16] = O01[r];
        mO[slot1][quad * 4 + r][l16]      = O10[r];
        mO[slot1][16 + quad * 4 + r][l16] = O11[r];
    }
    if (quad == 0) {
        mL[slot0 * 16 + l16] = la;
        mL[slot1 * 16 + l16] = lb;
    }
    __syncthreads();

    // 512 threads -> (h1, dg): 64 x 8 float4 outputs; 4-way kq sum
    const int h1 = tid >> 3;             // 0..63
    const int dg = tid & 7;              // 0..7 -> d = dg*4
    const int qg_o = h1 >> 4, ql = h1 & 15;
    const int qgp_o = qg_o >> 1, g_o = qg_o & 1;
    // slot for quarter kq: ((kq*2 + qgp_o)*2 + g_o)
    float denom = 0.f;
    float4 o = {0.f, 0.f, 0.f, 0.f};
    #pragma unroll
    for (int kqe = 0; kqe < 4; kqe++) {
        const int s = ((kqe * 2 + qgp_o) << 1) + g_o;
        denom += mL[s * 16 + ql];
        o.x += mO[s][dg * 4 + 0][ql];
        o.y += mO[s][dg * 4 + 1][ql];
        o.z += mO[s][dg * 4 + 2][ql];
        o.w += mO[s][dg * 4 + 3][ql];
    }
    const float inv = 1.0f / denom;
    o.x *= inv; o.y *= inv; o.z *= inv; o.w *= inv;
    const int head = bn & 3, bb = bn >> 2;
    *(float4*)&out[(((size_t)bb * 64 + h1) * 64 + w1) * 128 + head * 32 + dg * 4] = o;
}

// ---------------------------------------------------------------------------
extern "C" void kernel_launch(void* const* d_in, const int* in_sizes, int n_in,
                              void* d_out, int out_size, void* d_ws, size_t ws_size,
                              hipStream_t stream) {
    const float* x     = (const float*)d_in[0];   // [2,64,64,128]
    const float* w_qkv = (const float*)d_in[1];   // [128,384]
    const float* emb_h = (const float*)d_in[2];   // [127,32]
    const float* emb_w = (const float*)d_in[3];   // [127,32]
    float* out = (float*)d_out;

    // workspace: q_h/k_h/vt_h 1M halfs each
    _Float16* q_h  = (_Float16*)d_ws;
    _Float16* k_h  = q_h + (size_t)BN_ * L_ * KD;
    _Float16* vt_h = k_h + (size_t)BN_ * L_ * KD;

    qkv_gemm<<<768, 256, 0, stream>>>(x, w_qkv, q_h, k_h, vt_h);
    attn_mfma<<<512, 512, 0, stream>>>(q_h, k_h, vt_h, emb_h, emb_w, out);
}

// Round 15
// 98.747 us; speedup vs baseline: 1.0203x; 1.0203x over previous
//
#include <hip/hip_runtime.h>
#include <hip/hip_bf16.h>
#include <math.h>

// Problem constants (fixed by setup_inputs)
#define B_  2
#define NH  4
#define HH  64
#define WW  64
#define KD  32
#define L_  4096            // HH*WW
#define BN_ 8               // B_*NH
#define LOG2E 1.4426950408889634f
#define KSCALE (0.17677669529663687f * 1.4426950408889634f)  // log2e/sqrt(32)
#define FIXED_M 10.0f   // log2-domain fixed softmax shift (shift-invariant =>
                        // exact); scores max ~3, p=2^(s-10) f16-safe to s>26.

typedef float    f32x4  __attribute__((ext_vector_type(4), may_alias));
typedef _Float16 half8  __attribute__((ext_vector_type(8), may_alias));
typedef _Float16 half4  __attribute__((ext_vector_type(4), may_alias));
typedef __fp16   fp16x2 __attribute__((ext_vector_type(2)));
typedef unsigned uint4v __attribute__((ext_vector_type(4), may_alias));

__device__ __forceinline__ float fexp2(float x) {
#if __has_builtin(__builtin_amdgcn_exp2f)
    return __builtin_amdgcn_exp2f(x);
#else
    return __expf(x * 0.69314718056f);
#endif
}

__device__ __forceinline__ unsigned pack2u(float a, float b) {
    fp16x2 t = __builtin_amdgcn_cvt_pkrtz(a, b);   // v_cvt_pkrtz_f16_f32
    union { fp16x2 i; unsigned o; } u;
    u.i = t;
    return u.o;
}

// ---------------------------------------------------------------------------
// Kernel A: qkv = x @ w_qkv (M=8192,K=128,N=384), f16 MFMA, single LDS pass
// (K=128), wsT-staged. Outputs: q_h/k_h [bn][l][32] (k pre-scaled),
// TILE-PACKED V (R13 layout).
// ---------------------------------------------------------------------------
__global__ __launch_bounds__(256) void qkv_gemm(const float* __restrict__ x,
                                                const float* __restrict__ w,
                                                _Float16* __restrict__ q_h,
                                                _Float16* __restrict__ k_h,
                                                _Float16* __restrict__ vt_h) {
    __shared__ __align__(16) char smem[34816];
    _Float16* xs  = (_Float16*)smem;            // [64][136]
    _Float16* wsT = (_Float16*)(smem + 17408);  // [64][136] transposed w

    const int mt = blockIdx.x % 128;
    const int nt = blockIdx.x / 128;
    const int m0 = mt * 64, n0 = nt * 64;
    const int tid = threadIdx.x;
    const int wv = tid >> 6, lane = tid & 63;
    const int l16 = lane & 15, quad = lane >> 4;

    #pragma unroll
    for (int i = 0; i < 8; i++) {
        const int idx = i * 256 + tid;
        const int row = idx >> 5, c4 = (idx & 31) * 4;
        const float4 v = *(const float4*)&x[(size_t)(m0 + row) * 128 + c4];
        half4 h;
        h[0] = (_Float16)v.x; h[1] = (_Float16)v.y;
        h[2] = (_Float16)v.z; h[3] = (_Float16)v.w;
        *(half4*)&xs[row * 136 + c4] = h;
    }
    #pragma unroll
    for (int i = 0; i < 8; i++) {
        const int idx = i * 256 + tid;
        const int k = idx >> 4, c4 = (idx & 15) * 4;
        const float4 v = *(const float4*)&w[(size_t)k * 384 + n0 + c4];
        wsT[(c4 + 0) * 136 + k] = (_Float16)v.x;
        wsT[(c4 + 1) * 136 + k] = (_Float16)v.y;
        wsT[(c4 + 2) * 136 + k] = (_Float16)v.z;
        wsT[(c4 + 3) * 136 + k] = (_Float16)v.w;
    }
    __syncthreads();

    f32x4 acc[4] = {{0.f,0.f,0.f,0.f},{0.f,0.f,0.f,0.f},
                    {0.f,0.f,0.f,0.f},{0.f,0.f,0.f,0.f}};
    half8 af[4];
    #pragma unroll
    for (int kc = 0; kc < 4; kc++)
        af[kc] = *(const half8*)&xs[(wv * 16 + l16) * 136 + kc * 32 + quad * 8];
    #pragma unroll
    for (int ns = 0; ns < 4; ns++)
        #pragma unroll
        for (int kc = 0; kc < 4; kc++) {
            const half8 bf = *(const half8*)&wsT[(ns * 16 + l16) * 136 + kc * 32 + quad * 8];
            acc[ns] = __builtin_amdgcn_mfma_f32_16x16x32_f16(af[kc], bf, acc[ns], 0, 0, 0);
        }

    const int which = n0 >> 7;                 // 0=q, 1=k, 2=v
    const int nc = n0 & 127;
    const int b = m0 >> 12;
    if (which < 2) {
        _Float16* dst = (which == 0) ? q_h : k_h;
        const float mult = (which == 1) ? KSCALE : 1.0f;
        #pragma unroll
        for (int ns = 0; ns < 4; ns++) {
            const int col = nc + ns * 16 + l16;
            const int bn = b * NH + (col >> 5);
            const int d = col & 31;
            #pragma unroll
            for (int r = 0; r < 4; r++) {
                const int l = (m0 & 4095) + wv * 16 + quad * 4 + r;
                dst[((size_t)bn * L_ + l) * 32 + d] = (_Float16)(acc[ns][r] * mult);
            }
        }
    } else {
        __syncthreads();                        // xs dead -> overlay img
        float* img = (float*)smem;
        #pragma unroll
        for (int ns = 0; ns < 4; ns++) {
            const int chan = ns * 16 + l16;
            const int h = chan >> 5, d = chan & 31;
            #pragma unroll
            for (int r = 0; r < 4; r++) {
                const int p = wv * 16 + quad * 4 + r;
                const int y = p >> 5, p32 = p & 31;
                const int q4 = (p32 >> 2) & 3;
                const int j = ((p32 >> 4) & 1) * 4 + (p32 & 3);
                const int fidx = h * 2048 + (y * 2 + (d >> 4)) * 512
                               + (q4 * 16 + (d & 15)) * 8 + j;
                img[fidx + (fidx >> 4)] = acc[ns][r];
            }
        }
        __syncthreads();
        const int ktg = (m0 & 4095) >> 6;
        #pragma unroll
        for (int h = 0; h < 2; h++) {
            const int head = (nc >> 5) + h;
            const int bn = b * NH + head;
            const int fbase = h * 2048 + tid * 8;
            const int sbase = fbase + (fbase >> 4);
            half8 o;
            #pragma unroll
            for (int e = 0; e < 8; e++) o[e] = (_Float16)img[sbase + e];
            *(half8*)(vt_h + (size_t)bn * 131072 + ktg * 2048 + tid * 8) = o;
        }
    }
}

// ---------------------------------------------------------------------------
// Kernel B: LDS-staged flash attention. R35 = R30 (best measured: 40.7us)
// + l-accumulation MOVED FROM VALU TO MFMA. Ledger after 15 rounds: read
// volume/waves/barriers/domains all null; body-widening spills (128-reg cap
// at 16-wave blocks); no pipe saturated (VALU 45%, MFMA 17%) -> convoy-
// latency bound. Last lever: the 16 v_dot2/wave-step on the busiest pipe
// (VALU) become 4 MFMAs on the 17%-idle matrix pipe: L = mfma(ones16x32, p,
// L) gives C[r][q] = sum_k P[q,k] (A=ones makes the tile-packing k-perm
// sum-invariant). Epilogue shuffles drop too (each lane's L[0] is already
// the full row sum). Everything else R30-verbatim: 16 waves = 4kq x 2qgp x
// 2wo, grid 256, 16 dbuf steps, [16][65] kt-indexed R-tables, staging
// lane-stride-16B. Spill tripwire: FETCH/WRITE balloon at pinned VGPR=64.
// ---------------------------------------------------------------------------
__global__ __launch_bounds__(1024) void attn_mfma(
    const _Float16* __restrict__ q_h,    // [bn][l][32]
    const _Float16* __restrict__ k_h,    // [bn][l][32] pre-scaled
    const _Float16* __restrict__ vt_h,   // [bn][kt][2048] tile-packed
    const float* __restrict__ emb_h,     // [127][32] f32
    const float* __restrict__ emb_w,     // [127][32] f32
    float* __restrict__ out)
{
    // [0,65536): K/V stage, 2 bufs x 32KB; buffer layout:
    //   [0,16K) K quarters 0..3 (4KB each) | [16K,32K) V quarters 0..3
    // [65536,98816): 8 R-tables [16][65] f32 (merge overlays smem after loop)
    __shared__ __align__(16) char smem[98816];

    const int bi    = blockIdx.x;
    const int bn    = bi & 7;            // XCD swizzle: one bn per XCD
    const int wpair = bi >> 3;           // 0..31 -> w1 = wpair*2 + wo
    const int tid   = threadIdx.x;
    const int wv    = tid >> 6;          // 0..15
    const int kq    = wv >> 2;           // key quarter 0..3 (16-tile ring)
    const int qgp   = (wv >> 1) & 1;     // q-group pair
    const int wo    = wv & 1;            // w1 offset within pair
    const int w1    = wpair * 2 + wo;
    const int lane  = tid & 63;
    const int l16   = lane & 15;
    const int quad  = lane >> 4;
    const int q0A   = (qgp * 2 + 0) * 16;   // h1 base, q-group A
    const int q0B   = (qgp * 2 + 1) * 16;   // h1 base, q-group B

    const _Float16* Kbase = k_h  + (size_t)bn * L_ * 32;
    const _Float16* Vtile = vt_h + (size_t)bn * 131072;

    // ---- staging: category = (kqS, isVS); 2 waves/cat, 2x1KB chunks each ----
    const int cat  = wv & 7;
    const int kqS  = cat & 3;
    const int isVS = cat >> 2;
    const int halfS = wv >> 3;           // chunk-pair selector
    const _Float16* gsrc = (isVS ? Vtile : Kbase) + (size_t)kqS * 16 * 2048;
    const _Float16* gs[2];
    int ldsT[2];
    #pragma unroll
    for (int u = 0; u < 2; u++) {
        const int cc = halfS * 2 + u;    // 1KB chunk 0..3 within the 4KB tile
        gs[u] = gsrc + cc * 512 + lane * 8;
        // per-instruction address pattern identical to R24 (lane-stride 16B)
        ldsT[u] = kqS * 4096 + isVS * 16384 + (isVS
            ? (cc * 1024 + lane * 16)
            : ((cc * 16 + (lane >> 2)) * 64 + (((lane & 3) ^ ((lane >> 3) & 3)) << 4)));
    }

    // ---- prologue: issue stage for step 0 (hides under R-phase) ----
    const uint4v stg0a = *(const uint4v*)gs[0];
    const uint4v stg0b = *(const uint4v*)gs[1];

    // R tables: index (qg, wo); this wave's two tables
    float* RwA = (float*)(smem + 65536) + ((qgp * 2 + 0) * 2 + wo) * 1040;
    float* RwB = (float*)(smem + 65536) + ((qgp * 2 + 1) * 2 + wo) * 1040;

    const half8 aq0 = *(const half8*)(q_h +
        (((size_t)bn * L_ + (q0A + l16) * 64 + w1) * 32 + quad * 8));
    const half8 aq1 = *(const half8*)(q_h +
        (((size_t)bn * L_ + (q0B + l16) * 64 + w1) * 32 + quad * 8));

    f32x4 qwT0[4], qwT1[4];
    #pragma unroll
    for (int sub = 0; sub < 4; sub++) {
        const float* ew = emb_w + (size_t)(sub * 16 + l16 - w1 + 63) * 32 + quad * 8;
        const float4 e0 = *(const float4*)ew;
        const float4 e1 = *(const float4*)(ew + 4);
        union { uint4v u; half8 h; } ua;
        ua.u[0] = pack2u(e0.x * LOG2E, e0.y * LOG2E);
        ua.u[1] = pack2u(e0.z * LOG2E, e0.w * LOG2E);
        ua.u[2] = pack2u(e1.x * LOG2E, e1.y * LOG2E);
        ua.u[3] = pack2u(e1.z * LOG2E, e1.w * LOG2E);
        f32x4 z = {-FIXED_M, -FIXED_M, -FIXED_M, -FIXED_M};
        qwT0[sub] = __builtin_amdgcn_mfma_f32_16x16x32_f16(ua.h, aq0, z, 0, 0, 0);
        qwT1[sub] = __builtin_amdgcn_mfma_f32_16x16x32_f16(ua.h, aq1, z, 0, 0, 0);
    }

    // h-bias fill: kt-indexed, predicated. Wave (kq,qgp,wo) covers jt=kq*2+ji
    // for BOTH its q-group tables; 4 kq waves cover j 0..127.
    #pragma unroll
    for (int ji = 0; ji < 2; ji++) {
        const int jt = kq * 2 + ji;
        const int j = min(jt * 16 + l16, 126);
        const float* eh = emb_h + (size_t)j * 32 + quad * 8;
        const float4 e0 = *(const float4*)eh;
        const float4 e1 = *(const float4*)(eh + 4);
        union { uint4v u; half8 h; } ub;
        ub.u[0] = pack2u(e0.x * LOG2E, e0.y * LOG2E);
        ub.u[1] = pack2u(e0.z * LOG2E, e0.w * LOG2E);
        ub.u[2] = pack2u(e1.x * LOG2E, e1.y * LOG2E);
        ub.u[3] = pack2u(e1.z * LOG2E, e1.w * LOG2E);
        f32x4 z = {0.f, 0.f, 0.f, 0.f};
        const f32x4 C0 = __builtin_amdgcn_mfma_f32_16x16x32_f16(aq0, ub.h, z, 0, 0, 0);
        const f32x4 C1 = __builtin_amdgcn_mfma_f32_16x16x32_f16(aq1, ub.h, z, 0, 0, 0);
        #pragma unroll
        for (int r = 0; r < 4; r++) {
            const int row = quad * 4 + r;
            const int cA = jt * 16 + l16 - 63 + (q0A + row);   // = kt
            if (cA >= 0 && cA < 64) RwA[row * 65 + cA] = C0[r];
            const int cB = jt * 16 + l16 - 63 + (q0B + row);
            if (cB >= 0 && cB < 64) RwB[row * 65 + cB] = C1[r];
        }
    }

    // write prologue stage (vmcnt wait is ~free: issued way up top)
    *(uint4v*)(smem + ldsT[0]) = stg0a;
    *(uint4v*)(smem + ldsT[1]) = stg0b;
    __syncthreads();    // R tables + step-0 tiles ready

    f32x4 O00 = {0.f,0.f,0.f,0.f}, O01 = {0.f,0.f,0.f,0.f};   // g=0
    f32x4 O10 = {0.f,0.f,0.f,0.f}, O11 = {0.f,0.f,0.f,0.f};   // g=1
    f32x4 L0  = {0.f,0.f,0.f,0.f}, L1  = {0.f,0.f,0.f,0.f};   // l row-sums
    half8 onesA;
    {
        union { unsigned u[4]; half8 h; } uo;
        const unsigned one2 = pack2u(1.0f, 1.0f);
        uo.u[0] = one2; uo.u[1] = one2; uo.u[2] = one2; uo.u[3] = one2;
        onesA = uo.h;
    }
    const float* qh_rowA = RwA + l16 * 65;
    const float* qh_rowB = RwB + l16 * 65;

    // per-lane read offsets (constant across steps)
    const int swz16 = ((quad ^ ((l16 >> 1) & 3)) << 4);
    const int kOff = kq * 4096 + l16 * 64 + swz16;
    const int vOff = 16384 + kq * 4096 + lane * 16;

    #pragma unroll 2
    for (int t = 0; t < 16; t++) {
        const int cur = t & 1;
        const int tS = (t < 15) ? (t + 1) : 15;       // clamp: last re-reads t15
        // ---- issue next-step stage loads (latency hides under compute) ----
        const uint4v sa = *(const uint4v*)(gs[0] + (size_t)tS * 2048);
        const uint4v sb = *(const uint4v*)(gs[1] + (size_t)tS * 2048);

        const char* kb = smem + cur * 32768 + kOff;
        const char* vb = smem + cur * 32768 + vOff;
        const half8 kf0 = *(const half8*)(kb);
        const half8 kf1 = *(const half8*)(kb + 1024);
        const half8 kf2 = *(const half8*)(kb + 2048);
        const half8 kf3 = *(const half8*)(kb + 3072);
        const half8 va00 = *(const half8*)(vb);
        const half8 va10 = *(const half8*)(vb + 1024);
        const half8 va01 = *(const half8*)(vb + 2048);
        const half8 va11 = *(const half8*)(vb + 3072);

        // ---- S for both q-groups from the SAME kf reads ----
        const f32x4 S00 = __builtin_amdgcn_mfma_f32_16x16x32_f16(kf0, aq0, qwT0[0], 0, 0, 0);
        const f32x4 S01 = __builtin_amdgcn_mfma_f32_16x16x32_f16(kf1, aq0, qwT0[1], 0, 0, 0);
        const f32x4 S02 = __builtin_amdgcn_mfma_f32_16x16x32_f16(kf2, aq0, qwT0[2], 0, 0, 0);
        const f32x4 S03 = __builtin_amdgcn_mfma_f32_16x16x32_f16(kf3, aq0, qwT0[3], 0, 0, 0);
        const f32x4 S10 = __builtin_amdgcn_mfma_f32_16x16x32_f16(kf0, aq1, qwT1[0], 0, 0, 0);
        const f32x4 S11 = __builtin_amdgcn_mfma_f32_16x16x32_f16(kf1, aq1, qwT1[1], 0, 0, 0);
        const f32x4 S12 = __builtin_amdgcn_mfma_f32_16x16x32_f16(kf2, aq1, qwT1[2], 0, 0, 0);
        const f32x4 S13 = __builtin_amdgcn_mfma_f32_16x16x32_f16(kf3, aq1, qwT1[3], 0, 0, 0);

        const int kt = kq * 16 + t;
        const float qhA = qh_rowA[kt];
        const float qhB = qh_rowB[kt];

        // ---- fixed-m softmax g=0 ----
        union { uint4v u; half8 h; } p0a, p0b;
        {
            const float a0 = fexp2(S00[0] + qhA), a1 = fexp2(S00[1] + qhA);
            const float a2 = fexp2(S00[2] + qhA), a3 = fexp2(S00[3] + qhA);
            const float a4 = fexp2(S01[0] + qhA), a5 = fexp2(S01[1] + qhA);
            const float a6 = fexp2(S01[2] + qhA), a7 = fexp2(S01[3] + qhA);
            p0a.u[0] = pack2u(a0, a1); p0a.u[1] = pack2u(a2, a3);
            p0a.u[2] = pack2u(a4, a5); p0a.u[3] = pack2u(a6, a7);
            const float b0 = fexp2(S02[0] + qhA), b1 = fexp2(S02[1] + qhA);
            const float b2 = fexp2(S02[2] + qhA), b3 = fexp2(S02[3] + qhA);
            const float b4 = fexp2(S03[0] + qhA), b5 = fexp2(S03[1] + qhA);
            const float b6 = fexp2(S03[2] + qhA), b7 = fexp2(S03[3] + qhA);
            p0b.u[0] = pack2u(b0, b1); p0b.u[1] = pack2u(b2, b3);
            p0b.u[2] = pack2u(b4, b5); p0b.u[3] = pack2u(b6, b7);
        }
        // ---- fixed-m softmax g=1 (independent chain) ----
        union { uint4v u; half8 h; } p1a, p1b;
        {
            const float a0 = fexp2(S10[0] + qhB), a1 = fexp2(S10[1] + qhB);
            const float a2 = fexp2(S10[2] + qhB), a3 = fexp2(S10[3] + qhB);
            const float a4 = fexp2(S11[0] + qhB), a5 = fexp2(S11[1] + qhB);
            const float a6 = fexp2(S11[2] + qhB), a7 = fexp2(S11[3] + qhB);
            p1a.u[0] = pack2u(a0, a1); p1a.u[1] = pack2u(a2, a3);
            p1a.u[2] = pack2u(a4, a5); p1a.u[3] = pack2u(a6, a7);
            const float b0 = fexp2(S12[0] + qhB), b1 = fexp2(S12[1] + qhB);
            const float b2 = fexp2(S12[2] + qhB), b3 = fexp2(S12[3] + qhB);
            const float b4 = fexp2(S13[0] + qhB), b5 = fexp2(S13[1] + qhB);
            const float b6 = fexp2(S13[2] + qhB), b7 = fexp2(S13[3] + qhB);
            p1b.u[0] = pack2u(b0, b1); p1b.u[1] = pack2u(b2, b3);
            p1b.u[2] = pack2u(b4, b5); p1b.u[3] = pack2u(b6, b7);
        }

        // ---- PV + l row-sums, all on the MFMA pipe ----
        O00 = __builtin_amdgcn_mfma_f32_16x16x32_f16(va00, p0a.h, O00, 0, 0, 0);
        O00 = __builtin_amdgcn_mfma_f32_16x16x32_f16(va01, p0b.h, O00, 0, 0, 0);
        O01 = __builtin_amdgcn_mfma_f32_16x16x32_f16(va10, p0a.h, O01, 0, 0, 0);
        O01 = __builtin_amdgcn_mfma_f32_16x16x32_f16(va11, p0b.h, O01, 0, 0, 0);
        O10 = __builtin_amdgcn_mfma_f32_16x16x32_f16(va00, p1a.h, O10, 0, 0, 0);
        O10 = __builtin_amdgcn_mfma_f32_16x16x32_f16(va01, p1b.h, O10, 0, 0, 0);
        O11 = __builtin_amdgcn_mfma_f32_16x16x32_f16(va10, p1a.h, O11, 0, 0, 0);
        O11 = __builtin_amdgcn_mfma_f32_16x16x32_f16(va11, p1b.h, O11, 0, 0, 0);
        // l: C[r][q] = sum_k 1 * P[q,k]  (k-permutation sum-invariant)
        L0  = __builtin_amdgcn_mfma_f32_16x16x32_f16(onesA, p0a.h, L0, 0, 0, 0);
        L0  = __builtin_amdgcn_mfma_f32_16x16x32_f16(onesA, p0b.h, L0, 0, 0, 0);
        L1  = __builtin_amdgcn_mfma_f32_16x16x32_f16(onesA, p1a.h, L1, 0, 0, 0);
        L1  = __builtin_amdgcn_mfma_f32_16x16x32_f16(onesA, p1b.h, L1, 0, 0, 0);

        // ---- write staged tile into the other buffer, then step barrier ----
        __builtin_amdgcn_sched_barrier(0);   // keep compute above the write
        *(uint4v*)(smem + (cur ^ 1) * 32768 + ldsT[0]) = sa;
        *(uint4v*)(smem + (cur ^ 1) * 32768 + ldsT[1]) = sb;
        __syncthreads();
    }

    __syncthreads();                     // stage+R dead -> overlay merge
    float (*mO)[32][17] = (float(*)[32][17])smem;     // [slot][d][q16], 32 slots
    float* mL = (float*)(smem + 69632);               // [slot][16]
    const int slot0 = wv * 2 + 0;        // g=0
    const int slot1 = wv * 2 + 1;        // g=1
    #pragma unroll
    for (int r = 0; r < 4; r++) {
        mO[slot0][quad * 4 + r][l16]      = O00[r];
        mO[slot0][16 + quad * 4 + r][l16] = O01[r];
        mO[slot1][quad * 4 + r][l16]      = O10[r];
        mO[slot1][16 + quad * 4 + r][l16] = O11[r];
    }
    if (quad == 0) {
        mL[slot0 * 16 + l16] = L0[0];    // all 4 rows equal; full q-row sum
        mL[slot1 * 16 + l16] = L1[0];
    }
    __syncthreads();

    // 1024 threads -> (wo_o, h1, dg): 2 x 64 x 8 float4 outputs; 4-way kq sum
    const int wo_o = tid >> 9;           // 0..1
    const int rest = tid & 511;
    const int h1   = rest >> 3;          // 0..63
    const int dg   = rest & 7;           // 0..7 -> d = dg*4
    const int qg_o = h1 >> 4, ql = h1 & 15;
    const int qgp_o = qg_o >> 1, g_o = qg_o & 1;
    // slot for quarter kq: ((kq*4 + qgp_o*2 + wo_o)*2 + g_o)
    float denom = 0.f;
    float4 o = {0.f, 0.f, 0.f, 0.f};
    #pragma unroll
    for (int kqe = 0; kqe < 4; kqe++) {
        const int s = ((kqe * 4 + qgp_o * 2 + wo_o) << 1) + g_o;
        denom += mL[s * 16 + ql];
        o.x += mO[s][dg * 4 + 0][ql];
        o.y += mO[s][dg * 4 + 1][ql];
        o.z += mO[s][dg * 4 + 2][ql];
        o.w += mO[s][dg * 4 + 3][ql];
    }
    const float inv = 1.0f / denom;
    o.x *= inv; o.y *= inv; o.z *= inv; o.w *= inv;
    const int head = bn & 3, bb = bn >> 2;
    const int w1o = wpair * 2 + wo_o;
    *(float4*)&out[(((size_t)bb * 64 + h1) * 64 + w1o) * 128 + head * 32 + dg * 4] = o;
}

// ---------------------------------------------------------------------------
extern "C" void kernel_launch(void* const* d_in, const int* in_sizes, int n_in,
                              void* d_out, int out_size, void* d_ws, size_t ws_size,
                              hipStream_t stream) {
    const float* x     = (const float*)d_in[0];   // [2,64,64,128]
    const float* w_qkv = (const float*)d_in[1];   // [128,384]
    const float* emb_h = (const float*)d_in[2];   // [127,32]
    const float* emb_w = (const float*)d_in[3];   // [127,32]
    float* out = (float*)d_out;

    // workspace: q_h/k_h/vt_h 1M halfs each
    _Float16* q_h  = (_Float16*)d_ws;
    _Float16* k_h  = q_h + (size_t)BN_ * L_ * KD;
    _Float16* vt_h = k_h + (size_t)BN_ * L_ * KD;

    qkv_gemm<<<768, 256, 0, stream>>>(x, w_qkv, q_h, k_h, vt_h);
    attn_mfma<<<256, 1024, 0, stream>>>(q_h, k_h, vt_h, emb_h, emb_w, out);
}